// Round 1
// 3474.117 us; speedup vs baseline: 1.0113x; 1.0113x over previous
//
#include <hip/hip_runtime.h>
#include <cstdint>
#include <cstddef>

#define DD 1024
#define SS 2048
#define BB 2
#define HH 16
#define HDD 64
#define FFD 4096
#define LL 6
#define VV 32000

typedef short s16x8 __attribute__((ext_vector_type(8)));
typedef float f32x4 __attribute__((ext_vector_type(4)));

__device__ __forceinline__ unsigned short f2bf(float f) {
    union { float f; unsigned int u; } v; v.f = f;
    unsigned int u = v.u;
    unsigned int r = (u + 0x7fffu + ((u >> 16) & 1u)) >> 16;
    return (unsigned short)r;
}

// async 16B global -> LDS (DMA; LDS dest must be wave-uniform base + lane*16)
__device__ __forceinline__ void async16(const unsigned short* g, unsigned short* l) {
    __builtin_amdgcn_global_load_lds((const __attribute__((address_space(1))) void*)g,
                                     (__attribute__((address_space(3))) void*)l, 16, 0, 0);
}

// ---------------- embedding + positional encoding ----------------
__global__ __launch_bounds__(256) void embed_kernel(const int* __restrict__ tokens,
        const float* __restrict__ emb, float* __restrict__ x,
        unsigned short* __restrict__ xb) {
    int row = blockIdx.x;              // b*S + s
    int s = row & (SS - 1);
    int tok = tokens[row];
    const float* erow = emb + (size_t)tok * DD;
    int t = threadIdx.x;
#pragma unroll
    for (int i = 0; i < 4; ++i) {
        int d = t + i * 256;
        float div = __expf((float)(d & ~1) * (-9.210340371976184f / (float)DD));
        float ang = (float)s * div;
        float pe = (d & 1) ? cosf(ang) : sinf(ang);
        float v = erow[d] + pe;
        x[(size_t)row * DD + d] = v;
        xb[(size_t)row * DD + d] = f2bf(v);
    }
}

// ---------------- fp32 [K][N] -> bf16 [N][K] transpose ----------------
__global__ __launch_bounds__(256) void transpose_bf16_kernel(const float* __restrict__ in,
        unsigned short* __restrict__ out, int K, int N) {
    __shared__ float tile[32][33];
    int n0 = blockIdx.x * 32, k0 = blockIdx.y * 32;
    int tx = threadIdx.x, ty = threadIdx.y;   // blockDim (32,8)
#pragma unroll
    for (int i = 0; i < 4; ++i) {
        int k = ty + i * 8;
        tile[k][tx] = in[(size_t)(k0 + k) * N + n0 + tx];
    }
    __syncthreads();
#pragma unroll
    for (int i = 0; i < 4; ++i) {
        int n = ty + i * 8;
        out[(size_t)(n0 + n) * K + k0 + tx] = f2bf(tile[tx][n]);
    }
}

// ---------------- generic bf16 MFMA GEMM: C[M,N] = A[M,K] * BT[N,K]^T + bias ----------------
// m97-rung structure: global_load_lds(16B) staging, linear LDS, XOR-swizzled
// source+read (seg ^= (row>>1)&3) so fragment ds_read_b128 is bank-conflict-free.
__global__ __launch_bounds__(256) void gemm_bt_kernel(const unsigned short* __restrict__ A,
        const unsigned short* __restrict__ BT, const float* __restrict__ bias,
        void* __restrict__ Cout, int M, int N, int K, int relu, int obf16) {
    __shared__ unsigned short As[128 * 32];   // [row][k8] linear, 64B rows
    __shared__ unsigned short Bs[128 * 32];
    int m0 = blockIdx.y * 128, n0 = blockIdx.x * 128;
    int t = threadIdx.x;
    int wv = t >> 6, lane = t & 63, quad = lane >> 4, l16 = lane & 15;
    int wm = wv & 1, wn = wv >> 1;
    const f32x4 fzero = {0.f, 0.f, 0.f, 0.f};
    f32x4 acc[4][4];
#pragma unroll
    for (int mt = 0; mt < 4; ++mt)
#pragma unroll
        for (int nt = 0; nt < 4; ++nt) acc[mt][nt] = fzero;

    // per-thread staging geometry: segment e = t + c*256, row = e>>2, seg16B = e&3
    // global source k-chunk is pre-swizzled so linear LDS holds swizzled data
    for (int k0 = 0; k0 < K; k0 += 32) {
        __syncthreads();
        const unsigned short* Ab = A + (size_t)m0 * K + k0;
        const unsigned short* Bb = BT + (size_t)n0 * K + k0;
#pragma unroll
        for (int c = 0; c < 2; ++c) {
            int e = t + c * 256;
            int r = e >> 2;
            int sk = ((e & 3) ^ ((r >> 1) & 3)) * 8;
            async16(Ab + (size_t)r * K + sk, &As[e * 8]);
            async16(Bb + (size_t)r * K + sk, &Bs[e * 8]);
        }
        __syncthreads();   // drains vmcnt: staged data visible
        s16x8 af[4], bf[4];
#pragma unroll
        for (int mt = 0; mt < 4; ++mt) {
            int row = wm * 64 + mt * 16 + l16;
            af[mt] = *(const s16x8*)&As[row * 32 + ((quad ^ ((row >> 1) & 3)) * 8)];
        }
#pragma unroll
        for (int nt = 0; nt < 4; ++nt) {
            int row = wn * 64 + nt * 16 + l16;
            bf[nt] = *(const s16x8*)&Bs[row * 32 + ((quad ^ ((row >> 1) & 3)) * 8)];
        }
#pragma unroll
        for (int mt = 0; mt < 4; ++mt)
#pragma unroll
            for (int nt = 0; nt < 4; ++nt)
                acc[mt][nt] = __builtin_amdgcn_mfma_f32_16x16x32_bf16(af[mt], bf[nt], acc[mt][nt], 0, 0, 0);
    }
#pragma unroll
    for (int nt = 0; nt < 4; ++nt) {
        int col = n0 + wn * 64 + nt * 16 + l16;
        float bz = bias[col];
#pragma unroll
        for (int mt = 0; mt < 4; ++mt) {
#pragma unroll
            for (int r = 0; r < 4; ++r) {
                int row = m0 + wm * 64 + mt * 16 + quad * 4 + r;
                float v = acc[mt][nt][r] + bz;
                if (relu) v = fmaxf(v, 0.f);
                if (obf16) ((unsigned short*)Cout)[(size_t)row * N + col] = f2bf(v);
                else ((float*)Cout)[(size_t)row * N + col] = v;
            }
        }
    }
}

// ---------------- flash attention (causal), qkv bf16 (B,S,3,H,HD) -> o bf16 (B,S,D) ----------------
__global__ __launch_bounds__(256) void flash_kernel(const unsigned short* __restrict__ qkv,
        unsigned short* __restrict__ o) {
    __shared__ unsigned short Qs[128][72];
    __shared__ unsigned short Ks[64][72];
    __shared__ unsigned short VsT[64][72];
    __shared__ unsigned short Ps[4][32][72];
    int qt = blockIdx.x;       // 0..15 (q tile of 128)
    int bh = blockIdx.y;       // 0..31
    int b = bh >> 4, h = bh & 15;
    int t = threadIdx.x, w = t >> 6, lane = t & 63, quad = lane >> 4, l16 = lane & 15;
    const unsigned short* base = qkv + (size_t)b * SS * (3 * DD) + h * HDD;
    const unsigned short* qb = base;
    const unsigned short* kb = base + DD;
    const unsigned short* vb = base + 2 * DD;

    // stage Q tile (128 rows x 64 dims)
#pragma unroll
    for (int c = 0; c < 4; ++c) {
        int e = t + c * 256;
        int r = e >> 3, k8 = (e & 7) * 8;
        *(s16x8*)&Qs[r][k8] = *(const s16x8*)(qb + (size_t)(qt * 128 + r) * (3 * DD) + k8);
    }
    __syncthreads();
    s16x8 qf[2][2];
#pragma unroll
    for (int mt = 0; mt < 2; ++mt)
#pragma unroll
        for (int ks = 0; ks < 2; ++ks)
            qf[mt][ks] = *(const s16x8*)&Qs[w * 32 + mt * 16 + l16][ks * 32 + quad * 8];

    const f32x4 fzero = {0.f, 0.f, 0.f, 0.f};
    float mi[2][4], li[2][4];
    f32x4 oacc[2][4];
#pragma unroll
    for (int mt = 0; mt < 2; ++mt) {
#pragma unroll
        for (int r = 0; r < 4; ++r) { mi[mt][r] = -1e30f; li[mt][r] = 0.f; }
#pragma unroll
        for (int nt = 0; nt < 4; ++nt) oacc[mt][nt] = fzero;
    }

    int nkt = 2 * (qt + 1);   // 64-key tiles needed for causal coverage
    for (int kt = 0; kt < nkt; ++kt) {
        __syncthreads();
        // stage K tile (64 keys x 64 dims)
#pragma unroll
        for (int c = 0; c < 2; ++c) {
            int e = t + c * 256;
            int r = e >> 3, k8 = (e & 7) * 8;
            *(s16x8*)&Ks[r][k8] = *(const s16x8*)(kb + (size_t)(kt * 64 + r) * (3 * DD) + k8);
        }
        // stage V tile transposed: VsT[dim][key]
        {
            int key = t & 63, dh = (t >> 6) * 16;
            s16x8 v0 = *(const s16x8*)(vb + (size_t)(kt * 64 + key) * (3 * DD) + dh);
            s16x8 v1 = *(const s16x8*)(vb + (size_t)(kt * 64 + key) * (3 * DD) + dh + 8);
#pragma unroll
            for (int j = 0; j < 8; ++j) VsT[dh + j][key] = (unsigned short)v0[j];
#pragma unroll
            for (int j = 0; j < 8; ++j) VsT[dh + 8 + j][key] = (unsigned short)v1[j];
        }
        __syncthreads();
        // S = Q K^T  (32 q-rows per wave x 64 keys)
        f32x4 sf[2][4];
#pragma unroll
        for (int nt = 0; nt < 4; ++nt) {
            s16x8 kf0 = *(const s16x8*)&Ks[nt * 16 + l16][quad * 8];
            s16x8 kf1 = *(const s16x8*)&Ks[nt * 16 + l16][32 + quad * 8];
#pragma unroll
            for (int mt = 0; mt < 2; ++mt) {
                f32x4 s = fzero;
                s = __builtin_amdgcn_mfma_f32_16x16x32_bf16(qf[mt][0], kf0, s, 0, 0, 0);
                s = __builtin_amdgcn_mfma_f32_16x16x32_bf16(qf[mt][1], kf1, s, 0, 0, 0);
                sf[mt][nt] = s;
            }
        }
        // scale, causal mask, online softmax
        int ki0 = kt * 64 + l16;
#pragma unroll
        for (int mt = 0; mt < 2; ++mt) {
            int qrow = qt * 128 + w * 32 + mt * 16 + quad * 4;
#pragma unroll
            for (int r = 0; r < 4; ++r) {
                int qi = qrow + r;
                float mx = -1e30f;
#pragma unroll
                for (int nt = 0; nt < 4; ++nt) {
                    float sv = sf[mt][nt][r] * 0.125f;
                    sv = (ki0 + nt * 16 <= qi) ? sv : -1e30f;
                    sf[mt][nt][r] = sv;
                    mx = fmaxf(mx, sv);
                }
#pragma unroll
                for (int off = 8; off >= 1; off >>= 1) mx = fmaxf(mx, __shfl_xor(mx, off, 64));
                float mnew = fmaxf(mi[mt][r], mx);
                float alpha = __expf(mi[mt][r] - mnew);
                mi[mt][r] = mnew;
                float rs = 0.f;
#pragma unroll
                for (int nt = 0; nt < 4; ++nt) {
                    float p = __expf(sf[mt][nt][r] - mnew);
                    sf[mt][nt][r] = p;
                    rs += p;
                }
#pragma unroll
                for (int off = 8; off >= 1; off >>= 1) rs += __shfl_xor(rs, off, 64);
                li[mt][r] = li[mt][r] * alpha + rs;
#pragma unroll
                for (int nt = 0; nt < 4; ++nt) oacc[mt][nt][r] *= alpha;
            }
        }
        // P (C-layout) -> LDS (wave-private) -> A-layout
#pragma unroll
        for (int mt = 0; mt < 2; ++mt)
#pragma unroll
            for (int nt = 0; nt < 4; ++nt)
#pragma unroll
                for (int r = 0; r < 4; ++r)
                    Ps[w][mt * 16 + quad * 4 + r][nt * 16 + l16] = f2bf(sf[mt][nt][r]);
        __syncthreads();   // safety this round; Ps is wave-private
        // O += P V
#pragma unroll
        for (int ks = 0; ks < 2; ++ks) {
            s16x8 pf0 = *(const s16x8*)&Ps[w][l16][ks * 32 + quad * 8];
            s16x8 pf1 = *(const s16x8*)&Ps[w][16 + l16][ks * 32 + quad * 8];
#pragma unroll
            for (int nt = 0; nt < 4; ++nt) {
                s16x8 vf = *(const s16x8*)&VsT[nt * 16 + l16][ks * 32 + quad * 8];
                oacc[0][nt] = __builtin_amdgcn_mfma_f32_16x16x32_bf16(pf0, vf, oacc[0][nt], 0, 0, 0);
                oacc[1][nt] = __builtin_amdgcn_mfma_f32_16x16x32_bf16(pf1, vf, oacc[1][nt], 0, 0, 0);
            }
        }
    }
    // normalize and write O as bf16 into (B,S,D)
#pragma unroll
    for (int mt = 0; mt < 2; ++mt)
#pragma unroll
        for (int r = 0; r < 4; ++r) {
            float inv = 1.f / li[mt][r];
            int srow = qt * 128 + w * 32 + mt * 16 + quad * 4 + r;
#pragma unroll
            for (int nt = 0; nt < 4; ++nt)
                o[((size_t)b * SS + srow) * DD + h * HDD + nt * 16 + l16] =
                    f2bf(oacc[mt][nt][r] * inv);
        }
}

// ---------------- residual add + layernorm (row per block), writes x fp32 and xb bf16 ----------------
__global__ __launch_bounds__(256) void addln_kernel(float* __restrict__ x, const float* __restrict__ y,
        const float* __restrict__ g, const float* __restrict__ bb,
        unsigned short* __restrict__ xb) {
    int row = blockIdx.x;
    int t = threadIdx.x;
    __shared__ float red[8];
    float v[4];
    float s = 0.f;
#pragma unroll
    for (int i = 0; i < 4; ++i) {
        int d = t + i * 256;
        v[i] = x[(size_t)row * DD + d] + y[(size_t)row * DD + d];
        s += v[i];
    }
#pragma unroll
    for (int off = 32; off >= 1; off >>= 1) s += __shfl_xor(s, off, 64);
    if ((t & 63) == 0) red[t >> 6] = s;
    __syncthreads();
    float mu = (red[0] + red[1] + red[2] + red[3]) * (1.f / (float)DD);
    float sq = 0.f;
#pragma unroll
    for (int i = 0; i < 4; ++i) { v[i] -= mu; sq += v[i] * v[i]; }
#pragma unroll
    for (int off = 32; off >= 1; off >>= 1) sq += __shfl_xor(sq, off, 64);
    __syncthreads();
    if ((t & 63) == 0) red[t >> 6] = sq;
    __syncthreads();
    float var = (red[0] + red[1] + red[2] + red[3]) * (1.f / (float)DD);
    float rstd = rsqrtf(var + 1e-5f);
#pragma unroll
    for (int i = 0; i < 4; ++i) {
        int d = t + i * 256;
        float o = v[i] * rstd * g[d] + bb[d];
        x[(size_t)row * DD + d] = o;
        xb[(size_t)row * DD + d] = f2bf(o);
    }
}

extern "C" void kernel_launch(void* const* d_in, const int* in_sizes, int n_in,
                              void* d_out, int out_size, void* d_ws, size_t ws_size,
                              hipStream_t stream) {
    (void)in_sizes; (void)n_in; (void)out_size; (void)ws_size;
    const int*   tokens = (const int*)  d_in[0];
    const float* emb    = (const float*)d_in[1];
    const float* qkv_w  = (const float*)d_in[2];
    const float* qkv_b  = (const float*)d_in[3];
    const float* out_w  = (const float*)d_in[4];
    const float* out_b  = (const float*)d_in[5];
    const float* fc1_w  = (const float*)d_in[6];
    const float* fc1_b  = (const float*)d_in[7];
    const float* fc2_w  = (const float*)d_in[8];
    const float* fc2_b  = (const float*)d_in[9];
    const float* ln1_g  = (const float*)d_in[10];
    const float* ln1_b  = (const float*)d_in[11];
    const float* ln2_g  = (const float*)d_in[12];
    const float* ln2_b  = (const float*)d_in[13];
    const float* w_out  = (const float*)d_in[14];
    const float* b_out  = (const float*)d_in[15];

    char* ws = (char*)d_ws;
    size_t off = 0;
    auto alloc = [&](size_t bytes) -> void* {
        void* p = ws + off;
        off += (bytes + 255) & ~(size_t)255;
        return p;
    };
    const int R = BB * SS;                                   // 4096 token rows
    float*          x    = (float*)alloc((size_t)R * DD * 4);
    float*          y    = (float*)alloc((size_t)R * DD * 4);
    unsigned short* xb   = (unsigned short*)alloc((size_t)R * DD * 2);
    unsigned short* qkvb = (unsigned short*)alloc((size_t)R * 3 * DD * 2);
    unsigned short* ob   = (unsigned short*)alloc((size_t)R * DD * 2);
    unsigned short* hb   = (unsigned short*)alloc((size_t)R * FFD * 2);
    unsigned short* wT   = (unsigned short*)alloc((size_t)VV * DD * 2);

    embed_kernel<<<R, 256, 0, stream>>>(tokens, emb, x, xb);

    auto tr = [&](const float* w, int K, int N) {
        transpose_bf16_kernel<<<dim3(N / 32, K / 32), dim3(32, 8), 0, stream>>>(w, wT, K, N);
    };
    auto gemm = [&](const unsigned short* A, const float* bias, void* C,
                    int N, int K, int relu, int obf16) {
        gemm_bt_kernel<<<dim3(N / 128, R / 128), 256, 0, stream>>>(A, wT, bias, C, R, N, K, relu, obf16);
    };

    for (int l = 0; l < LL; ++l) {
        tr(qkv_w + (size_t)l * DD * 3 * DD, DD, 3 * DD);
        gemm(xb, qkv_b + (size_t)l * 3 * DD, qkvb, 3 * DD, DD, 0, 1);
        flash_kernel<<<dim3(SS / 128, BB * HH), 256, 0, stream>>>(qkvb, ob);
        tr(out_w + (size_t)l * DD * DD, DD, DD);
        gemm(ob, out_b + (size_t)l * DD, y, DD, DD, 0, 0);
        addln_kernel<<<R, 256, 0, stream>>>(x, y, ln1_g + (size_t)l * DD, ln1_b + (size_t)l * DD, xb);
        tr(fc1_w + (size_t)l * DD * FFD, DD, FFD);
        gemm(xb, fc1_b + (size_t)l * FFD, hb, FFD, DD, 1, 1);
        tr(fc2_w + (size_t)l * FFD * DD, FFD, DD);
        gemm(hb, fc2_b + (size_t)l * DD, y, DD, FFD, 0, 0);
        addln_kernel<<<R, 256, 0, stream>>>(x, y, ln2_g + (size_t)l * DD, ln2_b + (size_t)l * DD, xb);
    }
    tr(w_out, DD, VV);
    gemm(xb, b_out, d_out, VV, DD, 0, 0);
}